// Round 11
// baseline (1038.351 us; speedup 1.0000x reference)
//
#include <hip/hip_runtime.h>
#include <stdint.h>

#define BB 64
#define TT 512
#define DD 256
#define HH 512
#define NG 2048
#define BT (BB*TT)
#define NCLS 1000
#define MAXS 10

typedef _Float16 f16;
typedef _Float16 f16x2 __attribute__((ext_vector_type(2)));
typedef _Float16 f16x4 __attribute__((ext_vector_type(4)));
typedef _Float16 f16x8 __attribute__((ext_vector_type(8)));
typedef float f32x4 __attribute__((ext_vector_type(4)));

// bucket list offsets: OFF[s] = 64 * sum_{s'<s} ceil(512/(s'+1)); capacity 96192
__device__ const int d_OFF[MAXS] = {0,32768,49152,60096,68288,74880,80384,85120,89216,92864};

__device__ __forceinline__ float sigf(float x) { return 1.0f / (1.0f + __expf(-x)); }
__device__ __forceinline__ float tanh_(float x) {
  float e = __expf(-2.0f * fabsf(x));
  float r = (1.0f - e) / (1.0f + e);
  return copysignf(r, x);
}
__device__ __forceinline__ f32x4 mfma16(f16x8 a, f16x8 b, f32x4 c) {
  return __builtin_amdgcn_mfma_f32_16x16x32_f16(a, b, c, 0, 0, 0);
}
__device__ __forceinline__ void gload16(const void* g, void* l) {
  __builtin_amdgcn_global_load_lds((const __attribute__((address_space(1))) void*)g,
                                   (__attribute__((address_space(3))) void*)l, 16, 0, 0);
}

// ---------------- fused: weight casts + bias adds + x cast (one launch) ----------------
#define C0 (NG*DD/4)
#define C1 (C0 + NG*HH/4)
#define C2 (C1 + NG*HH/4)
#define C3 (C2 + NG*HH/4)
#define CX (C3 + BT*DD/4)
__global__ __launch_bounds__(256) void prep_weights(
    const float* __restrict__ Wih0, const float* __restrict__ Whh0,
    const float* __restrict__ Wih1, const float* __restrict__ Whh1,
    const float* __restrict__ x,
    const float* __restrict__ bih0, const float* __restrict__ bhh0,
    const float* __restrict__ bih1, const float* __restrict__ bhh1,
    f16* __restrict__ W16ih0, f16* __restrict__ W16hh0,
    f16* __restrict__ W16ih1, f16* __restrict__ W16hh1,
    f16* __restrict__ AX,
    float* __restrict__ bias0, float* __restrict__ bias1) {
  int gi = blockIdx.x * 256 + threadIdx.x;
  for (int i = gi; i < CX; i += gridDim.x * 256) {
    const float* s; f16* d; int o;
    if (i < C0)      { s = Wih0; d = W16ih0; o = i; }
    else if (i < C1) { s = Whh0; d = W16hh0; o = i - C0; }
    else if (i < C2) { s = Wih1; d = W16ih1; o = i - C1; }
    else if (i < C3) { s = Whh1; d = W16hh1; o = i - C2; }
    else             { s = x;    d = AX;     o = i - C3; }
    float4 v = ((const float4*)s)[o];
    f16x4 h = { (f16)v.x, (f16)v.y, (f16)v.z, (f16)v.w };
    ((f16x4*)d)[o] = h;
  }
  if (gi < NG/2) {
    int j = gi * 2;
    bias0[j]   = bih0[j]   + bhh0[j];
    bias0[j+1] = bih0[j+1] + bhh0[j+1];
    bias1[j]   = bih1[j]   + bhh1[j];
    bias1[j+1] = bih1[j+1] + bhh1[j+1];
  }
}

// ---------------- segment bucket lists + selm (run0 -> mask, else -1) ----------------
__global__ __launch_bounds__(512) void build_lists(const float* __restrict__ mask,
    int* __restrict__ counts, int* __restrict__ lists,
    int* __restrict__ tailcnt, int* __restrict__ taillist,
    float* __restrict__ selm) {
  int b = blockIdx.x, t = threadIdx.x;
  __shared__ float sm[512];
  __shared__ int lcnt[MAXS], lbase[MAXS];
  sm[t] = mask[b*TT + t];
  if (t < MAXS) lcnt[t] = 0;
  __syncthreads();
  int run = 0;
  for (int j = 1; j <= MAXS; ++j) {
    if (t - j < 0) break;
    if (sm[t - j] != 0.0f) run++; else break;
  }
  selm[b*TT + t] = (run == 0) ? sm[t] : -1.0f;
  bool tail = (run >= MAXS);
  int slot = -1;
  if (!tail && run > 0) slot = atomicAdd(&lcnt[run], 1);   // run0 handled in proj_act
  __syncthreads();
  if (t < MAXS) lbase[t] = atomicAdd(&counts[t*32], lcnt[t]);
  __syncthreads();
  if (!tail && run > 0) lists[d_OFF[run] + lbase[run] + slot] = b*TT + t;
  // ordered (by t) per-batch list of tail positions via block scan
  unsigned long long bal = __ballot(tail);
  int lane = t & 63, w = t >> 6;
  int wpre = __popcll(bal & ((1ull << lane) - 1ull));
  __shared__ int wsum[8];
  if (lane == 0) wsum[w] = __popcll(bal);
  __syncthreads();
  int base = 0;
  for (int i = 0; i < w; ++i) base += wsum[i];
  if (tail) taillist[b*TT + base + wpre] = t;
  if (t == 0) {
    int tot = 0;
    for (int i = 0; i < 8; ++i) tot += wsum[i];
    tailcnt[b] = tot;
  }
}

// ---------------- fused projection GEMM + inline step0 (m97 geometry) ----------------
// 256 thr / 4 waves, tile 128 rows x 128 cols (4 gates x 32 j), BK=64, As+Bs = 32KB.
__global__ __launch_bounds__(256) void proj_act(const f16* __restrict__ A,
    const f16* __restrict__ W, const float* __restrict__ bias,
    f16* __restrict__ G, f16* __restrict__ HS, f16* __restrict__ CS,
    const float* __restrict__ selm, int K) {
  __shared__ __align__(16) f16 smem[2*128*64];   // As | Bs ; reused as padded stage
  f16* As = smem;
  f16* Bs = smem + 128*64;
  __shared__ float sel[128];
  const int nwg = gridDim.x;                  // 2048, divisible by 8
  const int cpx = nwg >> 3;
  const int swz = (blockIdx.x & 7) * cpx + (blockIdx.x >> 3);
  const int m0 = (swz >> 4) * 128;
  const int j0 = (swz & 15) * 32;
  const int tid = threadIdx.x;
  const int lane = tid & 63;
  const int w = tid >> 6;
  if (tid < 128) sel[tid] = selm[m0 + tid];

  const f16* asrc[4];
  const f16* bsrc[4];
#pragma unroll
  for (int p = 0; p < 4; ++p) {
    int cid = tid + p*256;
    int r = cid >> 3, c = cid & 7;
    int cs = c ^ (r & 7);
    asrc[p] = A + (size_t)(m0 + r)*K + cs*8;
    int wrow = (r >> 5)*512 + j0 + (r & 31);   // B-stage row r -> gate r>>5, j-off r&31
    bsrc[p] = W + (size_t)wrow*K + cs*8;
  }

  const int wm = (w >> 1) * 64;
  const int wn = (w & 1) * 64;
  const int cl = lane & 15;
  const int kq = lane >> 4;
  f32x4 acc[4][4] = {};                       // [row-frag][col-frag]

  for (int k0 = 0; k0 < K; k0 += 64) {
#pragma unroll
    for (int p = 0; p < 4; ++p) {
      gload16(asrc[p] + k0, As + (tid + p*256)*8);
      gload16(bsrc[p] + k0, Bs + (tid + p*256)*8);
    }
    __syncthreads();
#pragma unroll
    for (int ks = 0; ks < 2; ++ks) {
      int kc = ks*4 + kq;
      f16x8 af[4], bf[4];
#pragma unroll
      for (int mi = 0; mi < 4; ++mi) {
        int row = wm + mi*16 + cl;
        af[mi] = *(const f16x8*)(As + row*64 + ((kc ^ (row & 7))*8));
      }
#pragma unroll
      for (int ni = 0; ni < 4; ++ni) {
        int brow = wn + ni*16 + cl;
        bf[ni] = *(const f16x8*)(Bs + brow*64 + ((kc ^ (brow & 7))*8));
      }
#pragma unroll
      for (int mi = 0; mi < 4; ++mi)
#pragma unroll
        for (int ni = 0; ni < 4; ++ni)
          acc[mi][ni] = mfma16(af[mi], bf[ni], acc[mi][ni]);
    }
    __syncthreads();
  }

  // bias: col c -> gate c>>5, j = j0 + (c&31)
#pragma unroll
  for (int ni = 0; ni < 4; ++ni) {
    int c = wn + ni*16 + cl;
    float bb = bias[(c >> 5)*512 + j0 + (c & 31)];
#pragma unroll
    for (int mi = 0; mi < 4; ++mi)
#pragma unroll
      for (int r = 0; r < 4; ++r)
        acc[mi][ni][r] += bb;
  }

  // padded LDS restage (2 halves of 64 rows), vectorized epilogue
  f16* stg = smem;                            // [64][136] = 17KB
#pragma unroll
  for (int half = 0; half < 2; ++half) {
    if ((w >> 1) == half) {
#pragma unroll
      for (int mi = 0; mi < 4; ++mi)
#pragma unroll
        for (int ni = 0; ni < 4; ++ni)
#pragma unroll
          for (int r = 0; r < 4; ++r) {
            int row_l = mi*16 + kq*4 + r;
            stg[row_l*136 + wn + ni*16 + cl] = (f16)acc[mi][ni][r];
          }
    }
    __syncthreads();
    {
      int row_l = tid >> 2, js = tid & 3;
      int slot = half*64 + row_l;
      int row = m0 + slot;
      int jj = j0 + js*8;
      const f16* sb = stg + row_l*136 + js*8;
      f16x8 vi = *(const f16x8*)(sb);
      f16x8 vf = *(const f16x8*)(sb + 32);
      f16x8 vg = *(const f16x8*)(sb + 64);
      f16x8 vo = *(const f16x8*)(sb + 96);
      float sm = sel[slot];
      if (sm >= 0.0f) {
        f16x8 hv, cv;
#pragma unroll
        for (int e = 0; e < 8; ++e) {
          float c = sigf((float)vi[e]) * tanh_((float)vg[e]);
          float h = sigf((float)vo[e]) * tanh_(c);
          hv[e] = (f16)(h*sm); cv[e] = (f16)(c*sm);
        }
        *(f16x8*)(HS + (size_t)row*HH + jj) = hv;
        *(f16x8*)(CS + (size_t)row*HH + jj) = cv;
      } else {
        *(f16x8*)(G + (size_t)row*NG +        jj) = vi;
        *(f16x8*)(G + (size_t)row*NG +  512 + jj) = vf;
        *(f16x8*)(G + (size_t)row*NG + 1024 + jj) = vg;
        *(f16x8*)(G + (size_t)row*NG + 1536 + jj) = vo;
      }
    }
    __syncthreads();
  }
}

// ---------------- bucket s (1..4): tiled MFMA step (m97 geometry, gathered rows) ----------------
__global__ __launch_bounds__(256) void lstm_step(const f16* __restrict__ Wh,
    const f16* __restrict__ G, f16* __restrict__ HS, f16* __restrict__ CS,
    const float* __restrict__ mask, const int* __restrict__ counts,
    const int* __restrict__ lists, int s) {
  const int cnt = counts[s*32];
  if (cnt == 0) return;
  const int units = ((cnt + 127) >> 7) * 16;
  const int* lst = lists + d_OFF[s];
  const int tid = threadIdx.x;
  const int lane = tid & 63;
  const int w = tid >> 6;
  __shared__ __align__(16) f16 smem[2*128*64];
  f16* As = smem;
  f16* Bs = smem + 128*64;
  __shared__ int ridx[128];
  __shared__ float rmk[128];
  const int wm = (w >> 1) * 64;
  const int wn = (w & 1) * 64;
  const int cl = lane & 15;
  const int kq = lane >> 4;

  for (int u = blockIdx.x; u < units; u += gridDim.x) {
    const int mbase = (u >> 4) * 128;
    const int j0 = (u & 15) * 32;
    if (tid < 128) {
      int i = mbase + tid;
      int r = (i < cnt) ? lst[i] : -1;
      ridx[tid] = r;
      rmk[tid] = (r >= 0) ? mask[r] : 0.0f;
    }
    __syncthreads();

    const f16* asrc[4];
    const f16* bsrc[4];
#pragma unroll
    for (int p = 0; p < 4; ++p) {
      int cid = tid + p*256;
      int r = cid >> 3, c = cid & 7;
      int cs = c ^ (r & 7);
      int rr = ridx[r];
      int sr = (rr >= 1 ? rr : 1) - 1;
      asrc[p] = HS + (size_t)sr*HH + cs*8;
      int wrow = (r >> 5)*512 + j0 + (r & 31);
      bsrc[p] = Wh + (size_t)wrow*HH + cs*8;
    }

    f32x4 acc[4][4] = {};
    for (int k0 = 0; k0 < HH; k0 += 64) {
#pragma unroll
      for (int p = 0; p < 4; ++p) {
        gload16(asrc[p] + k0, As + (tid + p*256)*8);
        gload16(bsrc[p] + k0, Bs + (tid + p*256)*8);
      }
      __syncthreads();
#pragma unroll
      for (int ks = 0; ks < 2; ++ks) {
        int kc = ks*4 + kq;
        f16x8 af[4], bf[4];
#pragma unroll
        for (int mi = 0; mi < 4; ++mi) {
          int row = wm + mi*16 + cl;
          af[mi] = *(const f16x8*)(As + row*64 + ((kc ^ (row & 7))*8));
        }
#pragma unroll
        for (int ni = 0; ni < 4; ++ni) {
          int brow = wn + ni*16 + cl;
          bf[ni] = *(const f16x8*)(Bs + brow*64 + ((kc ^ (brow & 7))*8));
        }
#pragma unroll
        for (int mi = 0; mi < 4; ++mi)
#pragma unroll
          for (int ni = 0; ni < 4; ++ni)
            acc[mi][ni] = mfma16(af[mi], bf[ni], acc[mi][ni]);
      }
      __syncthreads();
    }

    // padded LDS restage epilogue (vectorized G/CS/HS access)
    f16* stg = smem;
#pragma unroll
    for (int half = 0; half < 2; ++half) {
      if ((w >> 1) == half) {
#pragma unroll
        for (int mi = 0; mi < 4; ++mi)
#pragma unroll
          for (int ni = 0; ni < 4; ++ni)
#pragma unroll
            for (int r = 0; r < 4; ++r) {
              int row_l = mi*16 + kq*4 + r;
              stg[row_l*136 + wn + ni*16 + cl] = (f16)acc[mi][ni][r];
            }
      }
      __syncthreads();
      {
        int row_l = tid >> 2, js = tid & 3;
        int slot = half*64 + row_l;
        int row = ridx[slot];
        if (row >= 0) {
          int jj = j0 + js*8;
          const f16* sb = stg + row_l*136 + js*8;
          f16x8 ai  = *(const f16x8*)(sb);
          f16x8 af2 = *(const f16x8*)(sb + 32);
          f16x8 ag  = *(const f16x8*)(sb + 64);
          f16x8 ao  = *(const f16x8*)(sb + 96);
          f16x8 Gi = *(const f16x8*)(G + (size_t)row*NG +        jj);
          f16x8 Gf = *(const f16x8*)(G + (size_t)row*NG +  512 + jj);
          f16x8 Gg = *(const f16x8*)(G + (size_t)row*NG + 1024 + jj);
          f16x8 Go = *(const f16x8*)(G + (size_t)row*NG + 1536 + jj);
          f16x8 cp = *(const f16x8*)(CS + (size_t)(row - 1)*HH + jj);
          float m = rmk[slot];
          f16x8 hv, cv;
#pragma unroll
          for (int e = 0; e < 8; ++e) {
            float gi = (float)ai[e] + (float)Gi[e];
            float gf = (float)af2[e] + (float)Gf[e];
            float gg = (float)ag[e] + (float)Gg[e];
            float go = (float)ao[e] + (float)Go[e];
            float c = sigf(gf)*(float)cp[e] + sigf(gi)*tanh_(gg);
            float h = sigf(go)*tanh_(c);
            hv[e] = (f16)(h*m); cv[e] = (f16)(c*m);
          }
          *(f16x8*)(HS + (size_t)row*HH + jj) = hv;
          *(f16x8*)(CS + (size_t)row*HH + jj) = cv;
        }
      }
      __syncthreads();
    }
  }
}

// ---------------- bucket s (5..9): THIN tiled MFMA step (small counts), BK=64 ----------------
__global__ __launch_bounds__(512) void lstm_step_thin(const f16* __restrict__ Wh,
    const f16* __restrict__ G, f16* __restrict__ HS, f16* __restrict__ CS,
    const float* __restrict__ mask, const int* __restrict__ counts,
    const int* __restrict__ lists, int s) {
  const int cnt = counts[s*32];
  if (cnt == 0) return;
  const int units = ((cnt + 127) >> 7) * 32;
  const int* lst = lists + d_OFF[s];
  const int tid = threadIdx.x;
  const int lane = tid & 63;
  const int w = tid >> 6;
  __shared__ __align__(16) f16 As[128*64];   // 16KB
  __shared__ __align__(16) f16 Bs[64*64];    // 8KB: grow = gate*16 + jj
  __shared__ int ridx[128];
  __shared__ float rmk[128];
  const int cl = lane & 15;
  const int kq = lane >> 4;
  const int rbase = w * 16;

  for (int u = blockIdx.x; u < units; u += gridDim.x) {
    const int mbase = (u >> 5) * 128;
    const int j0 = (u & 31) * 16;
    if (tid < 128) {
      int i = mbase + tid;
      int r = (i < cnt) ? lst[i] : -1;
      ridx[tid] = r;
      rmk[tid] = (r >= 0) ? mask[r] : 0.0f;
    }
    __syncthreads();

    const f16* asrc[2];
#pragma unroll
    for (int p = 0; p < 2; ++p) {
      int cid = tid + p*512;
      int r = cid >> 3, c = cid & 7;
      int cs = c ^ (r & 7);
      int rr = ridx[r];
      int sr = (rr >= 1 ? rr : 1) - 1;
      asrc[p] = HS + (size_t)sr*HH + cs*8;
    }
    const f16* bsrc;
    {
      int grow = tid >> 3, c = tid & 7;
      int cs = c ^ (grow & 7);
      int wrow = (grow >> 4)*512 + j0 + (grow & 15);
      bsrc = Wh + (size_t)wrow*HH + cs*8;
    }

    f32x4 acc[4] = {};
    for (int k0 = 0; k0 < HH; k0 += 64) {
#pragma unroll
      for (int p = 0; p < 2; ++p)
        gload16(asrc[p] + k0, As + (tid + p*512)*8);
      gload16(bsrc + k0, Bs + tid*8);
      __syncthreads();
#pragma unroll
      for (int ks = 0; ks < 2; ++ks) {
        int kc = ks*4 + kq;
        int arow = rbase + cl;
        f16x8 af = *(const f16x8*)(As + arow*64 + ((kc ^ (arow & 7))*8));
        f16x8 bf[4];
#pragma unroll
        for (int g = 0; g < 4; ++g) {
          int brow = g*16 + cl;
          bf[g] = *(const f16x8*)(Bs + brow*64 + ((kc ^ (brow & 7))*8));
        }
#pragma unroll
        for (int g = 0; g < 4; ++g)
          acc[g] = mfma16(af, bf[g], acc[g]);
      }
      __syncthreads();
    }

    const int j = j0 + cl;
#pragma unroll
    for (int r = 0; r < 4; ++r) {
      int slot = rbase + kq*4 + r;
      int row = ridx[slot];
      if (row >= 0) {
        size_t gb = (size_t)row * NG;
        float gi = acc[0][r] + (float)G[gb + j];
        float gf = acc[1][r] + (float)G[gb + 512 + j];
        float gg = acc[2][r] + (float)G[gb + 1024 + j];
        float go = acc[3][r] + (float)G[gb + 1536 + j];
        float cp = (float)CS[(size_t)(row - 1)*HH + j];
        float c = sigf(gf)*cp + sigf(gi)*tanh_(gg);
        float h = sigf(go)*tanh_(c);
        float m = rmk[slot];
        HS[(size_t)row*HH + j] = (f16)(h*m);
        CS[(size_t)row*HH + j] = (f16)(c*m);
      }
    }
    __syncthreads();
  }
}

// ---------------- tail: run >= 10, sequential per batch (coalesced matvec) ----------------
__global__ __launch_bounds__(512) void lstm_tail(const f16* __restrict__ Wh,
    const f16* __restrict__ G, f16* __restrict__ HS, f16* __restrict__ CS,
    const float* __restrict__ mask, const int* __restrict__ tailcnt,
    const int* __restrict__ taillist) {
  int b = blockIdx.x;
  int n = tailcnt[b];
  if (n == 0) return;
  int tid = threadIdx.x, lane = tid & 63, w = tid >> 6;
  const int rl = lane >> 3;
  const int kb = (lane & 7) * 8;
  __shared__ __align__(16) f16 hsh[HH];
  __shared__ float gsh[NG];
  for (int i = 0; i < n; ++i) {
    int t = taillist[b*TT + i];
    size_t row = (size_t)b*TT + t;
    if (tid < 256)
      ((uint32_t*)hsh)[tid] = ((const uint32_t*)(HS + (row - 1)*HH))[tid];
    __syncthreads();
    f16x8 hreg[8];
#pragma unroll
    for (int kk = 0; kk < 8; ++kk)
      hreg[kk] = *(const f16x8*)(hsh + kb + kk*64);
#pragma unroll 2
    for (int batch = 0; batch < 32; ++batch) {
      int o = (w*32 + batch)*8 + rl;
      const f16* wrow = Wh + (size_t)o*HH + kb;
      float p = 0.0f;
#pragma unroll
      for (int kk = 0; kk < 8; ++kk) {
        f16x8 wv = *(const f16x8*)(wrow + kk*64);
        f16x2 w0 = {wv[0], wv[1]}, w1 = {wv[2], wv[3]}, w2 = {wv[4], wv[5]}, w3 = {wv[6], wv[7]};
        f16x2 h0 = {hreg[kk][0], hreg[kk][1]}, h1 = {hreg[kk][2], hreg[kk][3]},
              h2 = {hreg[kk][4], hreg[kk][5]}, h3 = {hreg[kk][6], hreg[kk][7]};
        p = __builtin_amdgcn_fdot2(w0, h0, p, false);
        p = __builtin_amdgcn_fdot2(w1, h1, p, false);
        p = __builtin_amdgcn_fdot2(w2, h2, p, false);
        p = __builtin_amdgcn_fdot2(w3, h3, p, false);
      }
      p += __shfl_xor(p, 1);
      p += __shfl_xor(p, 2);
      p += __shfl_xor(p, 4);
      if ((lane & 7) == 0) gsh[o] = p + (float)G[row*NG + o];
    }
    __syncthreads();
    {
      float cp = (float)CS[(row - 1)*HH + tid];
      float c = sigf(gsh[512 + tid])*cp + sigf(gsh[tid])*tanh_(gsh[1024 + tid]);
      float h = sigf(gsh[1536 + tid])*tanh_(c);
      float m = mask[row];
      HS[row*HH + tid] = (f16)(h*m);
      CS[row*HH + tid] = (f16)(c*m);
    }
    __syncthreads();
  }
}

// ---------------- relu + layernorm, wave-per-row ----------------
__global__ __launch_bounds__(512) void ln_relu(const f16* __restrict__ in,
    const float* __restrict__ g, const float* __restrict__ be,
    f16* __restrict__ out) {
  int lane = threadIdx.x & 63, w = threadIdx.x >> 6;
  int row = blockIdx.x * 8 + w;
  f16x8 hv = *(const f16x8*)(in + (size_t)row*HH + lane*8);
  float xv[8]; float s1 = 0.f, s2 = 0.f;
#pragma unroll
  for (int e = 0; e < 8; ++e) { float x = fmaxf((float)hv[e], 0.f); xv[e] = x; s1 += x; s2 += x*x; }
#pragma unroll
  for (int o = 1; o < 64; o <<= 1) { s1 += __shfl_xor(s1, o); s2 += __shfl_xor(s2, o); }
  float mu = s1 * (1.0f/512.0f);
  float var = s2 * (1.0f/512.0f) - mu*mu;
  float rs = rsqrtf(var + 1e-5f);
  f16x8 ov;
#pragma unroll
  for (int e = 0; e < 8; ++e) ov[e] = (f16)((xv[e] - mu)*rs*g[lane*8+e] + be[lane*8+e]);
  *(f16x8*)(out + (size_t)row*HH + lane*8) = ov;
}

// ---------------- fused head: relu+LN of last hidden state, then FC to 1000 classes ----------------
__global__ __launch_bounds__(512) void head_fused(const f16* __restrict__ HS,
    const float* __restrict__ g, const float* __restrict__ be,
    const float* __restrict__ W, const float* __restrict__ bias, float* __restrict__ out) {
  int b = blockIdx.x;
  int j = threadIdx.x;
  __shared__ float hsh[512];
  float x = fmaxf((float)HS[((size_t)b*TT + (TT-1))*HH + j], 0.0f);
  float s1 = x, s2 = x*x;
  for (int o = 32; o > 0; o >>= 1) { s1 += __shfl_down(s1, o); s2 += __shfl_down(s2, o); }
  __shared__ float a1[8], a2[8];
  int w = j >> 6;
  if ((j & 63) == 0) { a1[w] = s1; a2[w] = s2; }
  __syncthreads();
  if (j == 0) {
    float t1 = 0.f, t2 = 0.f;
    for (int i = 0; i < 8; ++i) { t1 += a1[i]; t2 += a2[i]; }
    a1[0] = t1; a2[0] = t2;
  }
  __syncthreads();
  float mu = a1[0] * (1.0f/512.0f);
  float var = a2[0] * (1.0f/512.0f) - mu*mu;
  hsh[j] = (x - mu) * rsqrtf(var + 1e-5f) * g[j] + be[j];
  __syncthreads();
#pragma unroll
  for (int rep = 0; rep < 2; ++rep) {
    int c = j + rep*512;
    if (c < NCLS) {
      const float4* wr = (const float4*)(W + (size_t)c*HH);
      float acc = bias[c];
#pragma unroll 4
      for (int k4 = 0; k4 < 128; ++k4) {
        float4 wv = wr[k4];
        acc += wv.x*hsh[k4*4] + wv.y*hsh[k4*4+1] + wv.z*hsh[k4*4+2] + wv.w*hsh[k4*4+3];
      }
      out[b*NCLS + c] = acc;
    }
  }
}

extern "C" void kernel_launch(void* const* d_in, const int* in_sizes, int n_in,
                              void* d_out, int out_size, void* d_ws, size_t ws_size,
                              hipStream_t stream) {
  (void)in_sizes; (void)n_in; (void)out_size;
  const float* x    = (const float*)d_in[0];
  const float* mask = (const float*)d_in[1];
  const float* Wih0 = (const float*)d_in[2];
  const float* Whh0 = (const float*)d_in[3];
  const float* bih0 = (const float*)d_in[4];
  const float* bhh0 = (const float*)d_in[5];
  const float* g0   = (const float*)d_in[6];
  const float* be0  = (const float*)d_in[7];
  const float* Wih1 = (const float*)d_in[8];
  const float* Whh1 = (const float*)d_in[9];
  const float* bih1 = (const float*)d_in[10];
  const float* bhh1 = (const float*)d_in[11];
  const float* g1   = (const float*)d_in[12];
  const float* be1  = (const float*)d_in[13];
  const float* fcW  = (const float*)d_in[14];
  const float* fcb  = (const float*)d_in[15];
  float* out = (float*)d_out;

  char* ws = (char*)d_ws;
  size_t off = 0;
  auto alloc = [&](size_t bytes) { size_t o = off; off += (bytes + 255) & ~(size_t)255; return o; };
  f16* G      = (f16*)(ws + alloc((size_t)BT*NG*2));
  f16* HS     = (f16*)(ws + alloc((size_t)BT*HH*2));
  f16* CS     = (f16*)(ws + alloc((size_t)BT*HH*2));
  f16* H0LN   = (f16*)(ws + alloc((size_t)BT*HH*2));
  f16* W16ih0 = (f16*)(ws + alloc((size_t)NG*DD*2));
  f16* W16hh0 = (f16*)(ws + alloc((size_t)NG*HH*2));
  f16* W16ih1 = (f16*)(ws + alloc((size_t)NG*HH*2));
  f16* W16hh1 = (f16*)(ws + alloc((size_t)NG*HH*2));
  float* bias0 = (float*)(ws + alloc(NG*4));
  float* bias1 = (float*)(ws + alloc(NG*4));
  int* counts  = (int*)(ws + alloc(4096));       // counts[s*32], s=0..9 | tailcnt @ +512
  int* tailcnt = counts + 512;
  int* lists   = (int*)(ws + alloc(96192*4));
  int* taillist= (int*)(ws + alloc((size_t)BT*4));
  float* selm  = (float*)(ws + alloc((size_t)BT*4));
  if (ws_size < off) return;

  f16* AX = H0LN;  // x-f16 region, consumed by proj_act L0 before H0LN written

  hipMemsetAsync(counts, 0, 4096, stream);
  prep_weights<<<dim3(512), dim3(256), 0, stream>>>(Wih0, Whh0, Wih1, Whh1, x,
      bih0, bhh0, bih1, bhh1, W16ih0, W16hh0, W16ih1, W16hh1, AX, bias0, bias1);
  build_lists<<<dim3(BB), dim3(512), 0, stream>>>(mask, counts, lists, tailcnt, taillist, selm);

  for (int layer = 0; layer < 2; ++layer) {
    const f16* Wih16 = layer ? W16ih1 : W16ih0;
    const f16* Whh16 = layer ? W16hh1 : W16hh0;
    const float* bias = layer ? bias1 : bias0;
    const f16* Ain = layer ? H0LN : AX;
    int K = layer ? HH : DD;
    proj_act<<<dim3((BT/128)*16), dim3(256), 0, stream>>>(Ain, Wih16, bias, G, HS, CS, selm, K);
    for (int s = 1; s < 5; ++s)
      lstm_step<<<dim3(1024), dim3(256), 0, stream>>>(Whh16, G, HS, CS, mask, counts, lists, s);
    for (int s = 5; s < MAXS; ++s)
      lstm_step_thin<<<dim3(256), dim3(512), 0, stream>>>(Whh16, G, HS, CS, mask, counts, lists, s);
    lstm_tail<<<dim3(BB), dim3(512), 0, stream>>>(Whh16, G, HS, CS, mask, tailcnt, taillist);
    if (layer == 0)
      ln_relu<<<dim3(BT/8), dim3(512), 0, stream>>>(HS, g0, be0, H0LN);
  }

  head_fused<<<dim3(BB), dim3(512), 0, stream>>>(HS, g1, be1, fcW, fcb, out);
}

// Round 12
// 933.138 us; speedup vs baseline: 1.1128x; 1.1128x over previous
//
#include <hip/hip_runtime.h>
#include <stdint.h>

#define BB 64
#define TT 512
#define DD 256
#define HH 512
#define NG 2048
#define BT (BB*TT)
#define NCLS 1000
#define MAXS 16

typedef _Float16 f16;
typedef _Float16 f16x2 __attribute__((ext_vector_type(2)));
typedef _Float16 f16x4 __attribute__((ext_vector_type(4)));
typedef _Float16 f16x8 __attribute__((ext_vector_type(8)));
typedef float f32x4 __attribute__((ext_vector_type(4)));

// bucket list offsets: OFF[s] = 64 * sum_{s'<s} ceil(512/(s'+1)); capacity 111168
__device__ const int d_OFF[MAXS] = {0,32768,49152,60096,68288,74880,80384,85120,
                                    89216,92864,96192,99200,101952,104512,106880,109120};

__device__ __forceinline__ float sigf(float x) { return 1.0f / (1.0f + __expf(-x)); }
__device__ __forceinline__ float tanh_(float x) {
  float e = __expf(-2.0f * fabsf(x));
  float r = (1.0f - e) / (1.0f + e);
  return copysignf(r, x);
}
__device__ __forceinline__ f32x4 mfma16(f16x8 a, f16x8 b, f32x4 c) {
  return __builtin_amdgcn_mfma_f32_16x16x32_f16(a, b, c, 0, 0, 0);
}
__device__ __forceinline__ void gload16(const void* g, void* l) {
  __builtin_amdgcn_global_load_lds((const __attribute__((address_space(1))) void*)g,
                                   (__attribute__((address_space(3))) void*)l, 16, 0, 0);
}

// ---------------- fused: weight casts + bias adds + x cast (one launch) ----------------
#define C0 (NG*DD/4)
#define C1 (C0 + NG*HH/4)
#define C2 (C1 + NG*HH/4)
#define C3 (C2 + NG*HH/4)
#define CX (C3 + BT*DD/4)
__global__ __launch_bounds__(256) void prep_weights(
    const float* __restrict__ Wih0, const float* __restrict__ Whh0,
    const float* __restrict__ Wih1, const float* __restrict__ Whh1,
    const float* __restrict__ x,
    const float* __restrict__ bih0, const float* __restrict__ bhh0,
    const float* __restrict__ bih1, const float* __restrict__ bhh1,
    f16* __restrict__ W16ih0, f16* __restrict__ W16hh0,
    f16* __restrict__ W16ih1, f16* __restrict__ W16hh1,
    f16* __restrict__ AX,
    float* __restrict__ bias0, float* __restrict__ bias1) {
  int gi = blockIdx.x * 256 + threadIdx.x;
  for (int i = gi; i < CX; i += gridDim.x * 256) {
    const float* s; f16* d; int o;
    if (i < C0)      { s = Wih0; d = W16ih0; o = i; }
    else if (i < C1) { s = Whh0; d = W16hh0; o = i - C0; }
    else if (i < C2) { s = Wih1; d = W16ih1; o = i - C1; }
    else if (i < C3) { s = Whh1; d = W16hh1; o = i - C2; }
    else             { s = x;    d = AX;     o = i - C3; }
    float4 v = ((const float4*)s)[o];
    f16x4 h = { (f16)v.x, (f16)v.y, (f16)v.z, (f16)v.w };
    ((f16x4*)d)[o] = h;
  }
  if (gi < NG/2) {
    int j = gi * 2;
    bias0[j]   = bih0[j]   + bhh0[j];
    bias0[j+1] = bih0[j+1] + bhh0[j+1];
    bias1[j]   = bih1[j]   + bhh1[j];
    bias1[j+1] = bih1[j+1] + bhh1[j+1];
  }
}

// ---------------- segment bucket lists + selm (run0 -> mask, else -1) ----------------
__global__ __launch_bounds__(512) void build_lists(const float* __restrict__ mask,
    int* __restrict__ counts, int* __restrict__ lists,
    int* __restrict__ tailcnt, int* __restrict__ taillist,
    float* __restrict__ selm) {
  int b = blockIdx.x, t = threadIdx.x;
  __shared__ float sm[512];
  __shared__ int lcnt[MAXS], lbase[MAXS];
  sm[t] = mask[b*TT + t];
  if (t < MAXS) lcnt[t] = 0;
  __syncthreads();
  int run = 0;
  for (int j = 1; j <= MAXS; ++j) {
    if (t - j < 0) break;
    if (sm[t - j] != 0.0f) run++; else break;
  }
  selm[b*TT + t] = (run == 0) ? sm[t] : -1.0f;
  bool tail = (run >= MAXS);
  int slot = -1;
  if (!tail && run > 0) slot = atomicAdd(&lcnt[run], 1);   // run0 handled in proj_act
  __syncthreads();
  if (t < MAXS) lbase[t] = atomicAdd(&counts[t*32], lcnt[t]);
  __syncthreads();
  if (!tail && run > 0) lists[d_OFF[run] + lbase[run] + slot] = b*TT + t;
  // ordered (by t) per-batch list of tail positions via block scan
  unsigned long long bal = __ballot(tail);
  int lane = t & 63, w = t >> 6;
  int wpre = __popcll(bal & ((1ull << lane) - 1ull));
  __shared__ int wsum[8];
  if (lane == 0) wsum[w] = __popcll(bal);
  __syncthreads();
  int base = 0;
  for (int i = 0; i < w; ++i) base += wsum[i];
  if (tail) taillist[b*TT + base + wpre] = t;
  if (t == 0) {
    int tot = 0;
    for (int i = 0; i < 8; ++i) tot += wsum[i];
    tailcnt[b] = tot;
  }
}

// ---------------- fused projection GEMM + inline step0 (m97 geometry) ----------------
// 256 thr / 4 waves, tile 128 rows x 128 cols (4 gates x 32 j), BK=64, As+Bs = 32KB.
__global__ __launch_bounds__(256) void proj_act(const f16* __restrict__ A,
    const f16* __restrict__ W, const float* __restrict__ bias,
    f16* __restrict__ G, f16* __restrict__ HS, f16* __restrict__ CS,
    const float* __restrict__ selm, int K) {
  __shared__ __align__(16) f16 smem[2*128*64];   // As | Bs ; reused as padded stage
  f16* As = smem;
  f16* Bs = smem + 128*64;
  __shared__ float sel[128];
  const int nwg = gridDim.x;                  // 4096, divisible by 8
  const int cpx = nwg >> 3;
  const int swz = (blockIdx.x & 7) * cpx + (blockIdx.x >> 3);
  const int m0 = (swz >> 4) * 128;
  const int j0 = (swz & 15) * 32;
  const int tid = threadIdx.x;
  const int lane = tid & 63;
  const int w = tid >> 6;
  if (tid < 128) sel[tid] = selm[m0 + tid];

  const f16* asrc[4];
  const f16* bsrc[4];
#pragma unroll
  for (int p = 0; p < 4; ++p) {
    int cid = tid + p*256;
    int r = cid >> 3, c = cid & 7;
    int cs = c ^ (r & 7);
    asrc[p] = A + (size_t)(m0 + r)*K + cs*8;
    int wrow = (r >> 5)*512 + j0 + (r & 31);   // B-stage row r -> gate r>>5, j-off r&31
    bsrc[p] = W + (size_t)wrow*K + cs*8;
  }

  const int wm = (w >> 1) * 64;
  const int wn = (w & 1) * 64;
  const int cl = lane & 15;
  const int kq = lane >> 4;
  f32x4 acc[4][4] = {};                       // [row-frag][col-frag]

  for (int k0 = 0; k0 < K; k0 += 64) {
#pragma unroll
    for (int p = 0; p < 4; ++p) {
      gload16(asrc[p] + k0, As + (tid + p*256)*8);
      gload16(bsrc[p] + k0, Bs + (tid + p*256)*8);
    }
    __syncthreads();
#pragma unroll
    for (int ks = 0; ks < 2; ++ks) {
      int kc = ks*4 + kq;
      f16x8 af[4], bf[4];
#pragma unroll
      for (int mi = 0; mi < 4; ++mi) {
        int row = wm + mi*16 + cl;
        af[mi] = *(const f16x8*)(As + row*64 + ((kc ^ (row & 7))*8));
      }
#pragma unroll
      for (int ni = 0; ni < 4; ++ni) {
        int brow = wn + ni*16 + cl;
        bf[ni] = *(const f16x8*)(Bs + brow*64 + ((kc ^ (brow & 7))*8));
      }
#pragma unroll
      for (int mi = 0; mi < 4; ++mi)
#pragma unroll
        for (int ni = 0; ni < 4; ++ni)
          acc[mi][ni] = mfma16(af[mi], bf[ni], acc[mi][ni]);
    }
    __syncthreads();
  }

  // bias: col c -> gate c>>5, j = j0 + (c&31)
#pragma unroll
  for (int ni = 0; ni < 4; ++ni) {
    int c = wn + ni*16 + cl;
    float bb = bias[(c >> 5)*512 + j0 + (c & 31)];
#pragma unroll
    for (int mi = 0; mi < 4; ++mi)
#pragma unroll
      for (int r = 0; r < 4; ++r)
        acc[mi][ni][r] += bb;
  }

  // padded LDS restage (2 halves of 64 rows), vectorized epilogue
  f16* stg = smem;                            // [64][136] = 17KB
#pragma unroll
  for (int half = 0; half < 2; ++half) {
    if ((w >> 1) == half) {
#pragma unroll
      for (int mi = 0; mi < 4; ++mi)
#pragma unroll
        for (int ni = 0; ni < 4; ++ni)
#pragma unroll
          for (int r = 0; r < 4; ++r) {
            int row_l = mi*16 + kq*4 + r;
            stg[row_l*136 + wn + ni*16 + cl] = (f16)acc[mi][ni][r];
          }
    }
    __syncthreads();
    {
      int row_l = tid >> 2, js = tid & 3;
      int slot = half*64 + row_l;
      int row = m0 + slot;
      int jj = j0 + js*8;
      const f16* sb = stg + row_l*136 + js*8;
      f16x8 vi = *(const f16x8*)(sb);
      f16x8 vf = *(const f16x8*)(sb + 32);
      f16x8 vg = *(const f16x8*)(sb + 64);
      f16x8 vo = *(const f16x8*)(sb + 96);
      float sm = sel[slot];
      if (sm >= 0.0f) {
        f16x8 hv, cv;
#pragma unroll
        for (int e = 0; e < 8; ++e) {
          float c = sigf((float)vi[e]) * tanh_((float)vg[e]);
          float h = sigf((float)vo[e]) * tanh_(c);
          hv[e] = (f16)(h*sm); cv[e] = (f16)(c*sm);
        }
        *(f16x8*)(HS + (size_t)row*HH + jj) = hv;
        *(f16x8*)(CS + (size_t)row*HH + jj) = cv;
      } else {
        *(f16x8*)(G + (size_t)row*NG +        jj) = vi;
        *(f16x8*)(G + (size_t)row*NG +  512 + jj) = vf;
        *(f16x8*)(G + (size_t)row*NG + 1024 + jj) = vg;
        *(f16x8*)(G + (size_t)row*NG + 1536 + jj) = vo;
      }
    }
    __syncthreads();
  }
}

// ---------------- bucket s (1..4): tiled MFMA step (m97 geometry, gathered rows) ----------------
__global__ __launch_bounds__(256) void lstm_step(const f16* __restrict__ Wh,
    const f16* __restrict__ G, f16* __restrict__ HS, f16* __restrict__ CS,
    const float* __restrict__ mask, const int* __restrict__ counts,
    const int* __restrict__ lists, int s) {
  const int cnt = counts[s*32];
  if (cnt == 0) return;
  const int units = ((cnt + 127) >> 7) * 16;
  const int* lst = lists + d_OFF[s];
  const int tid = threadIdx.x;
  const int lane = tid & 63;
  const int w = tid >> 6;
  __shared__ __align__(16) f16 smem[2*128*64];
  f16* As = smem;
  f16* Bs = smem + 128*64;
  __shared__ int ridx[128];
  __shared__ float rmk[128];
  const int wm = (w >> 1) * 64;
  const int wn = (w & 1) * 64;
  const int cl = lane & 15;
  const int kq = lane >> 4;

  for (int u = blockIdx.x; u < units; u += gridDim.x) {
    const int mbase = (u >> 4) * 128;
    const int j0 = (u & 15) * 32;
    if (tid < 128) {
      int i = mbase + tid;
      int r = (i < cnt) ? lst[i] : -1;
      ridx[tid] = r;
      rmk[tid] = (r >= 0) ? mask[r] : 0.0f;
    }
    __syncthreads();

    const f16* asrc[4];
    const f16* bsrc[4];
#pragma unroll
    for (int p = 0; p < 4; ++p) {
      int cid = tid + p*256;
      int r = cid >> 3, c = cid & 7;
      int cs = c ^ (r & 7);
      int rr = ridx[r];
      int sr = (rr >= 1 ? rr : 1) - 1;
      asrc[p] = HS + (size_t)sr*HH + cs*8;
      int wrow = (r >> 5)*512 + j0 + (r & 31);
      bsrc[p] = Wh + (size_t)wrow*HH + cs*8;
    }

    f32x4 acc[4][4] = {};
    for (int k0 = 0; k0 < HH; k0 += 64) {
#pragma unroll
      for (int p = 0; p < 4; ++p) {
        gload16(asrc[p] + k0, As + (tid + p*256)*8);
        gload16(bsrc[p] + k0, Bs + (tid + p*256)*8);
      }
      __syncthreads();
#pragma unroll
      for (int ks = 0; ks < 2; ++ks) {
        int kc = ks*4 + kq;
        f16x8 af[4], bf[4];
#pragma unroll
        for (int mi = 0; mi < 4; ++mi) {
          int row = wm + mi*16 + cl;
          af[mi] = *(const f16x8*)(As + row*64 + ((kc ^ (row & 7))*8));
        }
#pragma unroll
        for (int ni = 0; ni < 4; ++ni) {
          int brow = wn + ni*16 + cl;
          bf[ni] = *(const f16x8*)(Bs + brow*64 + ((kc ^ (brow & 7))*8));
        }
#pragma unroll
        for (int mi = 0; mi < 4; ++mi)
#pragma unroll
          for (int ni = 0; ni < 4; ++ni)
            acc[mi][ni] = mfma16(af[mi], bf[ni], acc[mi][ni]);
      }
      __syncthreads();
    }

    // padded LDS restage epilogue (vectorized G/CS/HS access)
    f16* stg = smem;
#pragma unroll
    for (int half = 0; half < 2; ++half) {
      if ((w >> 1) == half) {
#pragma unroll
        for (int mi = 0; mi < 4; ++mi)
#pragma unroll
          for (int ni = 0; ni < 4; ++ni)
#pragma unroll
            for (int r = 0; r < 4; ++r) {
              int row_l = mi*16 + kq*4 + r;
              stg[row_l*136 + wn + ni*16 + cl] = (f16)acc[mi][ni][r];
            }
      }
      __syncthreads();
      {
        int row_l = tid >> 2, js = tid & 3;
        int slot = half*64 + row_l;
        int row = ridx[slot];
        if (row >= 0) {
          int jj = j0 + js*8;
          const f16* sb = stg + row_l*136 + js*8;
          f16x8 ai  = *(const f16x8*)(sb);
          f16x8 af2 = *(const f16x8*)(sb + 32);
          f16x8 ag  = *(const f16x8*)(sb + 64);
          f16x8 ao  = *(const f16x8*)(sb + 96);
          f16x8 Gi = *(const f16x8*)(G + (size_t)row*NG +        jj);
          f16x8 Gf = *(const f16x8*)(G + (size_t)row*NG +  512 + jj);
          f16x8 Gg = *(const f16x8*)(G + (size_t)row*NG + 1024 + jj);
          f16x8 Go = *(const f16x8*)(G + (size_t)row*NG + 1536 + jj);
          f16x8 cp = *(const f16x8*)(CS + (size_t)(row - 1)*HH + jj);
          float m = rmk[slot];
          f16x8 hv, cv;
#pragma unroll
          for (int e = 0; e < 8; ++e) {
            float gi = (float)ai[e] + (float)Gi[e];
            float gf = (float)af2[e] + (float)Gf[e];
            float gg = (float)ag[e] + (float)Gg[e];
            float go = (float)ao[e] + (float)Go[e];
            float c = sigf(gf)*(float)cp[e] + sigf(gi)*tanh_(gg);
            float h = sigf(go)*tanh_(c);
            hv[e] = (f16)(h*m); cv[e] = (f16)(c*m);
          }
          *(f16x8*)(HS + (size_t)row*HH + jj) = hv;
          *(f16x8*)(CS + (size_t)row*HH + jj) = cv;
        }
      }
      __syncthreads();
    }
  }
}

// ---------------- bucket s (5..15): THIN tiled MFMA step (small counts), BK=64 ----------------
__global__ __launch_bounds__(512) void lstm_step_thin(const f16* __restrict__ Wh,
    const f16* __restrict__ G, f16* __restrict__ HS, f16* __restrict__ CS,
    const float* __restrict__ mask, const int* __restrict__ counts,
    const int* __restrict__ lists, int s) {
  const int cnt = counts[s*32];
  if (cnt == 0) return;
  const int units = ((cnt + 127) >> 7) * 32;
  const int* lst = lists + d_OFF[s];
  const int tid = threadIdx.x;
  const int lane = tid & 63;
  const int w = tid >> 6;
  __shared__ __align__(16) f16 As[128*64];   // 16KB
  __shared__ __align__(16) f16 Bs[64*64];    // 8KB: grow = gate*16 + jj
  __shared__ int ridx[128];
  __shared__ float rmk[128];
  const int cl = lane & 15;
  const int kq = lane >> 4;
  const int rbase = w * 16;

  for (int u = blockIdx.x; u < units; u += gridDim.x) {
    const int mbase = (u >> 5) * 128;
    const int j0 = (u & 31) * 16;
    if (tid < 128) {
      int i = mbase + tid;
      int r = (i < cnt) ? lst[i] : -1;
      ridx[tid] = r;
      rmk[tid] = (r >= 0) ? mask[r] : 0.0f;
    }
    __syncthreads();

    const f16* asrc[2];
#pragma unroll
    for (int p = 0; p < 2; ++p) {
      int cid = tid + p*512;
      int r = cid >> 3, c = cid & 7;
      int cs = c ^ (r & 7);
      int rr = ridx[r];
      int sr = (rr >= 1 ? rr : 1) - 1;
      asrc[p] = HS + (size_t)sr*HH + cs*8;
    }
    const f16* bsrc;
    {
      int grow = tid >> 3, c = tid & 7;
      int cs = c ^ (grow & 7);
      int wrow = (grow >> 4)*512 + j0 + (grow & 15);
      bsrc = Wh + (size_t)wrow*HH + cs*8;
    }

    f32x4 acc[4] = {};
    for (int k0 = 0; k0 < HH; k0 += 64) {
#pragma unroll
      for (int p = 0; p < 2; ++p)
        gload16(asrc[p] + k0, As + (tid + p*512)*8);
      gload16(bsrc + k0, Bs + tid*8);
      __syncthreads();
#pragma unroll
      for (int ks = 0; ks < 2; ++ks) {
        int kc = ks*4 + kq;
        int arow = rbase + cl;
        f16x8 af = *(const f16x8*)(As + arow*64 + ((kc ^ (arow & 7))*8));
        f16x8 bf[4];
#pragma unroll
        for (int g = 0; g < 4; ++g) {
          int brow = g*16 + cl;
          bf[g] = *(const f16x8*)(Bs + brow*64 + ((kc ^ (brow & 7))*8));
        }
#pragma unroll
        for (int g = 0; g < 4; ++g)
          acc[g] = mfma16(af, bf[g], acc[g]);
      }
      __syncthreads();
    }

    const int j = j0 + cl;
#pragma unroll
    for (int r = 0; r < 4; ++r) {
      int slot = rbase + kq*4 + r;
      int row = ridx[slot];
      if (row >= 0) {
        size_t gb = (size_t)row * NG;
        float gi = acc[0][r] + (float)G[gb + j];
        float gf = acc[1][r] + (float)G[gb + 512 + j];
        float gg = acc[2][r] + (float)G[gb + 1024 + j];
        float go = acc[3][r] + (float)G[gb + 1536 + j];
        float cp = (float)CS[(size_t)(row - 1)*HH + j];
        float c = sigf(gf)*cp + sigf(gi)*tanh_(gg);
        float h = sigf(go)*tanh_(c);
        float m = rmk[slot];
        HS[(size_t)row*HH + j] = (f16)(h*m);
        CS[(size_t)row*HH + j] = (f16)(c*m);
      }
    }
    __syncthreads();
  }
}

// ---------------- tail: run >= 16, sequential per batch (rare; coalesced matvec) ----------------
__global__ __launch_bounds__(512) void lstm_tail(const f16* __restrict__ Wh,
    const f16* __restrict__ G, f16* __restrict__ HS, f16* __restrict__ CS,
    const float* __restrict__ mask, const int* __restrict__ tailcnt,
    const int* __restrict__ taillist) {
  int b = blockIdx.x;
  int n = tailcnt[b];
  if (n == 0) return;
  int tid = threadIdx.x, lane = tid & 63, w = tid >> 6;
  const int rl = lane >> 3;
  const int kb = (lane & 7) * 8;
  __shared__ __align__(16) f16 hsh[HH];
  __shared__ float gsh[NG];
  for (int i = 0; i < n; ++i) {
    int t = taillist[b*TT + i];
    size_t row = (size_t)b*TT + t;
    if (tid < 256)
      ((uint32_t*)hsh)[tid] = ((const uint32_t*)(HS + (row - 1)*HH))[tid];
    __syncthreads();
    f16x8 hreg[8];
#pragma unroll
    for (int kk = 0; kk < 8; ++kk)
      hreg[kk] = *(const f16x8*)(hsh + kb + kk*64);
#pragma unroll 2
    for (int batch = 0; batch < 32; ++batch) {
      int o = (w*32 + batch)*8 + rl;
      const f16* wrow = Wh + (size_t)o*HH + kb;
      float p = 0.0f;
#pragma unroll
      for (int kk = 0; kk < 8; ++kk) {
        f16x8 wv = *(const f16x8*)(wrow + kk*64);
        f16x2 w0 = {wv[0], wv[1]}, w1 = {wv[2], wv[3]}, w2 = {wv[4], wv[5]}, w3 = {wv[6], wv[7]};
        f16x2 h0 = {hreg[kk][0], hreg[kk][1]}, h1 = {hreg[kk][2], hreg[kk][3]},
              h2 = {hreg[kk][4], hreg[kk][5]}, h3 = {hreg[kk][6], hreg[kk][7]};
        p = __builtin_amdgcn_fdot2(w0, h0, p, false);
        p = __builtin_amdgcn_fdot2(w1, h1, p, false);
        p = __builtin_amdgcn_fdot2(w2, h2, p, false);
        p = __builtin_amdgcn_fdot2(w3, h3, p, false);
      }
      p += __shfl_xor(p, 1);
      p += __shfl_xor(p, 2);
      p += __shfl_xor(p, 4);
      if ((lane & 7) == 0) gsh[o] = p + (float)G[row*NG + o];
    }
    __syncthreads();
    {
      float cp = (float)CS[(row - 1)*HH + tid];
      float c = sigf(gsh[512 + tid])*cp + sigf(gsh[tid])*tanh_(gsh[1024 + tid]);
      float h = sigf(gsh[1536 + tid])*tanh_(c);
      float m = mask[row];
      HS[row*HH + tid] = (f16)(h*m);
      CS[row*HH + tid] = (f16)(c*m);
    }
    __syncthreads();
  }
}

// ---------------- relu + layernorm, wave-per-row ----------------
__global__ __launch_bounds__(512) void ln_relu(const f16* __restrict__ in,
    const float* __restrict__ g, const float* __restrict__ be,
    f16* __restrict__ out) {
  int lane = threadIdx.x & 63, w = threadIdx.x >> 6;
  int row = blockIdx.x * 8 + w;
  f16x8 hv = *(const f16x8*)(in + (size_t)row*HH + lane*8);
  float xv[8]; float s1 = 0.f, s2 = 0.f;
#pragma unroll
  for (int e = 0; e < 8; ++e) { float x = fmaxf((float)hv[e], 0.f); xv[e] = x; s1 += x; s2 += x*x; }
#pragma unroll
  for (int o = 1; o < 64; o <<= 1) { s1 += __shfl_xor(s1, o); s2 += __shfl_xor(s2, o); }
  float mu = s1 * (1.0f/512.0f);
  float var = s2 * (1.0f/512.0f) - mu*mu;
  float rs = rsqrtf(var + 1e-5f);
  f16x8 ov;
#pragma unroll
  for (int e = 0; e < 8; ++e) ov[e] = (f16)((xv[e] - mu)*rs*g[lane*8+e] + be[lane*8+e]);
  *(f16x8*)(out + (size_t)row*HH + lane*8) = ov;
}

// ---------------- fused head: relu+LN of last hidden state, then FC to 1000 classes ----------------
__global__ __launch_bounds__(512) void head_fused(const f16* __restrict__ HS,
    const float* __restrict__ g, const float* __restrict__ be,
    const float* __restrict__ W, const float* __restrict__ bias, float* __restrict__ out) {
  int b = blockIdx.x;
  int j = threadIdx.x;
  __shared__ float hsh[512];
  float x = fmaxf((float)HS[((size_t)b*TT + (TT-1))*HH + j], 0.0f);
  float s1 = x, s2 = x*x;
  for (int o = 32; o > 0; o >>= 1) { s1 += __shfl_down(s1, o); s2 += __shfl_down(s2, o); }
  __shared__ float a1[8], a2[8];
  int w = j >> 6;
  if ((j & 63) == 0) { a1[w] = s1; a2[w] = s2; }
  __syncthreads();
  if (j == 0) {
    float t1 = 0.f, t2 = 0.f;
    for (int i = 0; i < 8; ++i) { t1 += a1[i]; t2 += a2[i]; }
    a1[0] = t1; a2[0] = t2;
  }
  __syncthreads();
  float mu = a1[0] * (1.0f/512.0f);
  float var = a2[0] * (1.0f/512.0f) - mu*mu;
  hsh[j] = (x - mu) * rsqrtf(var + 1e-5f) * g[j] + be[j];
  __syncthreads();
#pragma unroll
  for (int rep = 0; rep < 2; ++rep) {
    int c = j + rep*512;
    if (c < NCLS) {
      const float4* wr = (const float4*)(W + (size_t)c*HH);
      float acc = bias[c];
#pragma unroll 4
      for (int k4 = 0; k4 < 128; ++k4) {
        float4 wv = wr[k4];
        acc += wv.x*hsh[k4*4] + wv.y*hsh[k4*4+1] + wv.z*hsh[k4*4+2] + wv.w*hsh[k4*4+3];
      }
      out[b*NCLS + c] = acc;
    }
  }
}

extern "C" void kernel_launch(void* const* d_in, const int* in_sizes, int n_in,
                              void* d_out, int out_size, void* d_ws, size_t ws_size,
                              hipStream_t stream) {
  (void)in_sizes; (void)n_in; (void)out_size;
  const float* x    = (const float*)d_in[0];
  const float* mask = (const float*)d_in[1];
  const float* Wih0 = (const float*)d_in[2];
  const float* Whh0 = (const float*)d_in[3];
  const float* bih0 = (const float*)d_in[4];
  const float* bhh0 = (const float*)d_in[5];
  const float* g0   = (const float*)d_in[6];
  const float* be0  = (const float*)d_in[7];
  const float* Wih1 = (const float*)d_in[8];
  const float* Whh1 = (const float*)d_in[9];
  const float* bih1 = (const float*)d_in[10];
  const float* bhh1 = (const float*)d_in[11];
  const float* g1   = (const float*)d_in[12];
  const float* be1  = (const float*)d_in[13];
  const float* fcW  = (const float*)d_in[14];
  const float* fcb  = (const float*)d_in[15];
  float* out = (float*)d_out;

  char* ws = (char*)d_ws;
  size_t off = 0;
  auto alloc = [&](size_t bytes) { size_t o = off; off += (bytes + 255) & ~(size_t)255; return o; };
  f16* G      = (f16*)(ws + alloc((size_t)BT*NG*2));
  f16* HS     = (f16*)(ws + alloc((size_t)BT*HH*2));
  f16* CS     = (f16*)(ws + alloc((size_t)BT*HH*2));
  f16* H0LN   = (f16*)(ws + alloc((size_t)BT*HH*2));
  f16* W16ih0 = (f16*)(ws + alloc((size_t)NG*DD*2));
  f16* W16hh0 = (f16*)(ws + alloc((size_t)NG*HH*2));
  f16* W16ih1 = (f16*)(ws + alloc((size_t)NG*HH*2));
  f16* W16hh1 = (f16*)(ws + alloc((size_t)NG*HH*2));
  float* bias0 = (float*)(ws + alloc(NG*4));
  float* bias1 = (float*)(ws + alloc(NG*4));
  int* counts  = (int*)(ws + alloc(4096));       // counts[s*32], s=0..15 | tailcnt @ +512
  int* tailcnt = counts + 512;
  int* lists   = (int*)(ws + alloc(111168*4));
  int* taillist= (int*)(ws + alloc((size_t)BT*4));
  float* selm  = (float*)(ws + alloc((size_t)BT*4));
  if (ws_size < off) return;

  f16* AX = H0LN;  // x-f16 region, consumed by proj_act L0 before H0LN written

  hipMemsetAsync(counts, 0, 4096, stream);
  prep_weights<<<dim3(512), dim3(256), 0, stream>>>(Wih0, Whh0, Wih1, Whh1, x,
      bih0, bhh0, bih1, bhh1, W16ih0, W16hh0, W16ih1, W16hh1, AX, bias0, bias1);
  build_lists<<<dim3(BB), dim3(512), 0, stream>>>(mask, counts, lists, tailcnt, taillist, selm);

  for (int layer = 0; layer < 2; ++layer) {
    const f16* Wih16 = layer ? W16ih1 : W16ih0;
    const f16* Whh16 = layer ? W16hh1 : W16hh0;
    const float* bias = layer ? bias1 : bias0;
    const f16* Ain = layer ? H0LN : AX;
    int K = layer ? HH : DD;
    proj_act<<<dim3((BT/128)*16), dim3(256), 0, stream>>>(Ain, Wih16, bias, G, HS, CS, selm, K);
    for (int s = 1; s < 5; ++s)
      lstm_step<<<dim3(1024), dim3(256), 0, stream>>>(Whh16, G, HS, CS, mask, counts, lists, s);
    for (int s = 5; s < MAXS; ++s)
      lstm_step_thin<<<dim3(256), dim3(512), 0, stream>>>(Whh16, G, HS, CS, mask, counts, lists, s);
    lstm_tail<<<dim3(BB), dim3(512), 0, stream>>>(Whh16, G, HS, CS, mask, tailcnt, taillist);
    if (layer == 0)
      ln_relu<<<dim3(BT/8), dim3(512), 0, stream>>>(HS, g0, be0, H0LN);
  }

  head_fused<<<dim3(BB), dim3(512), 0, stream>>>(HS, g1, be1, fcW, fcb, out);
}

// Round 13
// 817.914 us; speedup vs baseline: 1.2695x; 1.1409x over previous
//
#include <hip/hip_runtime.h>
#include <stdint.h>

#define BB 64
#define TT 512
#define DD 256
#define HH 512
#define NG 2048
#define BT (BB*TT)
#define NCLS 1000
#define MAXS 16

typedef _Float16 f16;
typedef _Float16 f16x2 __attribute__((ext_vector_type(2)));
typedef _Float16 f16x4 __attribute__((ext_vector_type(4)));
typedef _Float16 f16x8 __attribute__((ext_vector_type(8)));
typedef float f32x4 __attribute__((ext_vector_type(4)));

// bucket list offsets: OFF[s] = 64 * sum_{s'<s} ceil(512/(s'+1)); capacity 111168
__device__ const int d_OFF[MAXS] = {0,32768,49152,60096,68288,74880,80384,85120,
                                    89216,92864,96192,99200,101952,104512,106880,109120};

__device__ __forceinline__ float sigf(float x) { return 1.0f / (1.0f + __expf(-x)); }
__device__ __forceinline__ float tanh_(float x) {
  float e = __expf(-2.0f * fabsf(x));
  float r = (1.0f - e) / (1.0f + e);
  return copysignf(r, x);
}
__device__ __forceinline__ f32x4 mfma16(f16x8 a, f16x8 b, f32x4 c) {
  return __builtin_amdgcn_mfma_f32_16x16x32_f16(a, b, c, 0, 0, 0);
}
__device__ __forceinline__ void gload16(const void* g, void* l) {
  __builtin_amdgcn_global_load_lds((const __attribute__((address_space(1))) void*)g,
                                   (__attribute__((address_space(3))) void*)l, 16, 0, 0);
}

// ---------------- fused: weight casts + bias adds + x cast (one launch) ----------------
#define C0 (NG*DD/4)
#define C1 (C0 + NG*HH/4)
#define C2 (C1 + NG*HH/4)
#define C3 (C2 + NG*HH/4)
#define CX (C3 + BT*DD/4)
__global__ __launch_bounds__(256) void prep_weights(
    const float* __restrict__ Wih0, const float* __restrict__ Whh0,
    const float* __restrict__ Wih1, const float* __restrict__ Whh1,
    const float* __restrict__ x,
    const float* __restrict__ bih0, const float* __restrict__ bhh0,
    const float* __restrict__ bih1, const float* __restrict__ bhh1,
    f16* __restrict__ W16ih0, f16* __restrict__ W16hh0,
    f16* __restrict__ W16ih1, f16* __restrict__ W16hh1,
    f16* __restrict__ AX,
    float* __restrict__ bias0, float* __restrict__ bias1) {
  int gi = blockIdx.x * 256 + threadIdx.x;
  for (int i = gi; i < CX; i += gridDim.x * 256) {
    const float* s; f16* d; int o;
    if (i < C0)      { s = Wih0; d = W16ih0; o = i; }
    else if (i < C1) { s = Whh0; d = W16hh0; o = i - C0; }
    else if (i < C2) { s = Wih1; d = W16ih1; o = i - C1; }
    else if (i < C3) { s = Whh1; d = W16hh1; o = i - C2; }
    else             { s = x;    d = AX;     o = i - C3; }
    float4 v = ((const float4*)s)[o];
    f16x4 h = { (f16)v.x, (f16)v.y, (f16)v.z, (f16)v.w };
    ((f16x4*)d)[o] = h;
  }
  if (gi < NG/2) {
    int j = gi * 2;
    bias0[j]   = bih0[j]   + bhh0[j];
    bias0[j+1] = bih0[j+1] + bhh0[j+1];
    bias1[j]   = bih1[j]   + bhh1[j];
    bias1[j+1] = bih1[j+1] + bhh1[j+1];
  }
}

// ---------------- segment bucket lists + selm (run0 -> mask, else -1) ----------------
__global__ __launch_bounds__(512) void build_lists(const float* __restrict__ mask,
    int* __restrict__ counts, int* __restrict__ lists,
    int* __restrict__ tailcnt, int* __restrict__ taillist,
    float* __restrict__ selm) {
  int b = blockIdx.x, t = threadIdx.x;
  __shared__ float sm[512];
  __shared__ int lcnt[MAXS], lbase[MAXS];
  sm[t] = mask[b*TT + t];
  if (t < MAXS) lcnt[t] = 0;
  __syncthreads();
  int run = 0;
  for (int j = 1; j <= MAXS; ++j) {
    if (t - j < 0) break;
    if (sm[t - j] != 0.0f) run++; else break;
  }
  selm[b*TT + t] = (run == 0) ? sm[t] : -1.0f;
  bool tail = (run >= MAXS);
  int slot = -1;
  if (!tail && run > 0) slot = atomicAdd(&lcnt[run], 1);   // run0 handled in proj_act
  __syncthreads();
  if (t < MAXS) lbase[t] = atomicAdd(&counts[t*32], lcnt[t]);
  __syncthreads();
  if (!tail && run > 0) lists[d_OFF[run] + lbase[run] + slot] = b*TT + t;
  // ordered (by t) per-batch list of tail positions via block scan
  unsigned long long bal = __ballot(tail);
  int lane = t & 63, w = t >> 6;
  int wpre = __popcll(bal & ((1ull << lane) - 1ull));
  __shared__ int wsum[8];
  if (lane == 0) wsum[w] = __popcll(bal);
  __syncthreads();
  int base = 0;
  for (int i = 0; i < w; ++i) base += wsum[i];
  if (tail) taillist[b*TT + base + wpre] = t;
  if (t == 0) {
    int tot = 0;
    for (int i = 0; i < 8; ++i) tot += wsum[i];
    tailcnt[b] = tot;
  }
}

// ---------------- fused projection GEMM + inline step0 (512-thr, 804-us config) ----------------
__global__ __launch_bounds__(512) void proj_act(const f16* __restrict__ A,
    const f16* __restrict__ W, const float* __restrict__ bias,
    f16* __restrict__ G, f16* __restrict__ HS, f16* __restrict__ CS,
    const float* __restrict__ selm, int K) {
  __shared__ __align__(16) f16 smem[128*64 + 256*64];   // As | Bs ; reused as padded stage
  f16* As = smem;
  f16* Bs = smem + 128*64;
  __shared__ float sel[128];
  const int nwg = gridDim.x;                  // 2048, divisible by 8
  const int cpx = nwg >> 3;
  const int swz = (blockIdx.x & 7) * cpx + (blockIdx.x >> 3);
  const int m0 = (swz >> 3) * 128;
  const int j0 = (swz & 7) * 64;
  const int tid = threadIdx.x;
  const int lane = tid & 63;
  const int w = tid >> 6;
  if (tid < 128) sel[tid] = selm[m0 + tid];

  const f16* asrc[2];
#pragma unroll
  for (int p = 0; p < 2; ++p) {
    int cid = tid + p*512;
    int r = cid >> 3, c = cid & 7;
    int cs = c ^ (r & 7);
    asrc[p] = A + (size_t)(m0 + r)*K + cs*8;
  }
  const f16* bsrc[4];
#pragma unroll
  for (int p = 0; p < 4; ++p) {
    int cid = tid + p*512;
    int grow = cid >> 3, c = cid & 7;
    int cs = c ^ (grow & 7);
    int wrow = (grow >> 6)*512 + j0 + (grow & 63);
    bsrc[p] = W + (size_t)wrow*K + cs*8;
  }

  const int rg = w >> 2;
  const int jg = w & 3;
  const int cl = lane & 15;
  const int kq = lane >> 4;
  f32x4 acc[4][4] = {};                       // [row-frag][gate]

  for (int k0 = 0; k0 < K; k0 += 64) {
#pragma unroll
    for (int p = 0; p < 2; ++p)
      gload16(asrc[p] + k0, As + (tid + p*512)*8);
#pragma unroll
    for (int p = 0; p < 4; ++p)
      gload16(bsrc[p] + k0, Bs + (tid + p*512)*8);
    __syncthreads();
#pragma unroll
    for (int ks = 0; ks < 2; ++ks) {
      int kc = ks*4 + kq;
      f16x8 af[4], bf[4];
#pragma unroll
      for (int mi = 0; mi < 4; ++mi) {
        int row = rg*64 + mi*16 + cl;
        af[mi] = *(const f16x8*)(As + row*64 + ((kc ^ (row & 7))*8));
      }
#pragma unroll
      for (int g = 0; g < 4; ++g) {
        int brow = g*64 + jg*16 + cl;
        bf[g] = *(const f16x8*)(Bs + brow*64 + ((kc ^ (brow & 7))*8));
      }
#pragma unroll
      for (int mi = 0; mi < 4; ++mi)
#pragma unroll
        for (int g = 0; g < 4; ++g)
          acc[mi][g] = mfma16(af[mi], bf[g], acc[mi][g]);
    }
    __syncthreads();
  }

  // add bias (per thread: fixed j, 4 gates)
  const int j = j0 + jg*16 + cl;
#pragma unroll
  for (int g = 0; g < 4; ++g) {
    float bb = bias[g*512 + j];
#pragma unroll
    for (int mi = 0; mi < 4; ++mi)
#pragma unroll
      for (int r = 0; r < 4; ++r)
        acc[mi][g][r] += bb;
  }

  // padded LDS restage (2 halves of 64 rows), vectorized epilogue
  f16* stg = smem;                            // [64][264]
#pragma unroll
  for (int half = 0; half < 2; ++half) {
    if (rg == half) {
#pragma unroll
      for (int mi = 0; mi < 4; ++mi)
#pragma unroll
        for (int g = 0; g < 4; ++g)
#pragma unroll
          for (int r = 0; r < 4; ++r) {
            int row_l = mi*16 + kq*4 + r;
            stg[row_l*264 + g*64 + jg*16 + cl] = (f16)acc[mi][g][r];
          }
    }
    __syncthreads();
    {
      int row_l = tid >> 3, sl = tid & 7;
      int slot = half*64 + row_l;
      int row = m0 + slot;
      int jj = j0 + sl*8;
      f16x8 vi = *(const f16x8*)(stg + row_l*264 +        sl*8);
      f16x8 vf = *(const f16x8*)(stg + row_l*264 +  64 + sl*8);
      f16x8 vg = *(const f16x8*)(stg + row_l*264 + 128 + sl*8);
      f16x8 vo = *(const f16x8*)(stg + row_l*264 + 192 + sl*8);
      float sm = sel[slot];
      if (sm >= 0.0f) {
        f16x8 hv, cv;
#pragma unroll
        for (int e = 0; e < 8; ++e) {
          float c = sigf((float)vi[e]) * tanh_((float)vg[e]);
          float h = sigf((float)vo[e]) * tanh_(c);
          hv[e] = (f16)(h*sm); cv[e] = (f16)(c*sm);
        }
        *(f16x8*)(HS + (size_t)row*HH + jj) = hv;
        *(f16x8*)(CS + (size_t)row*HH + jj) = cv;
      } else {
        *(f16x8*)(G + (size_t)row*NG +        jj) = vi;
        *(f16x8*)(G + (size_t)row*NG +  512 + jj) = vf;
        *(f16x8*)(G + (size_t)row*NG + 1024 + jj) = vg;
        *(f16x8*)(G + (size_t)row*NG + 1536 + jj) = vo;
      }
    }
    __syncthreads();
  }
}

// ---------------- bucket s (1..4): tiled MFMA step (512-thr, 804-us config) ----------------
__global__ __launch_bounds__(512) void lstm_step(const f16* __restrict__ Wh,
    const f16* __restrict__ G, f16* __restrict__ HS, f16* __restrict__ CS,
    const float* __restrict__ mask, const int* __restrict__ counts,
    const int* __restrict__ lists, int s) {
  const int cnt = counts[s*32];
  if (cnt == 0) return;
  const int units = ((cnt + 127) >> 7) * 8;
  const int* lst = lists + d_OFF[s];
  const int tid = threadIdx.x;
  const int lane = tid & 63;
  const int w = tid >> 6;
  __shared__ __align__(16) f16 smem[128*64 + 256*64];
  f16* As = smem;
  f16* Bs = smem + 128*64;
  __shared__ int ridx[128];
  __shared__ float rmk[128];
  const int rg = w >> 2;
  const int jg = w & 3;
  const int cl = lane & 15;
  const int kq = lane >> 4;

  for (int u = blockIdx.x; u < units; u += gridDim.x) {
    const int mbase = (u >> 3) * 128;
    const int j0 = (u & 7) * 64;
    if (tid < 128) {
      int i = mbase + tid;
      int r = (i < cnt) ? lst[i] : -1;
      ridx[tid] = r;
      rmk[tid] = (r >= 0) ? mask[r] : 0.0f;
    }
    __syncthreads();

    const f16* asrc[2];
#pragma unroll
    for (int p = 0; p < 2; ++p) {
      int cid = tid + p*512;
      int r = cid >> 3, c = cid & 7;
      int cs = c ^ (r & 7);
      int rr = ridx[r];
      int sr = (rr >= 1 ? rr : 1) - 1;
      asrc[p] = HS + (size_t)sr*HH + cs*8;
    }
    const f16* bsrc[4];
#pragma unroll
    for (int p = 0; p < 4; ++p) {
      int cid = tid + p*512;
      int grow = cid >> 3, c = cid & 7;
      int cs = c ^ (grow & 7);
      int wrow = (grow >> 6)*512 + j0 + (grow & 63);
      bsrc[p] = Wh + (size_t)wrow*HH + cs*8;
    }

    f32x4 acc[4][4] = {};
    for (int k0 = 0; k0 < HH; k0 += 64) {
#pragma unroll
      for (int p = 0; p < 2; ++p)
        gload16(asrc[p] + k0, As + (tid + p*512)*8);
#pragma unroll
      for (int p = 0; p < 4; ++p)
        gload16(bsrc[p] + k0, Bs + (tid + p*512)*8);
      __syncthreads();
#pragma unroll
      for (int ks = 0; ks < 2; ++ks) {
        int kc = ks*4 + kq;
        f16x8 af[4], bf[4];
#pragma unroll
        for (int mi = 0; mi < 4; ++mi) {
          int row = rg*64 + mi*16 + cl;
          af[mi] = *(const f16x8*)(As + row*64 + ((kc ^ (row & 7))*8));
        }
#pragma unroll
        for (int g = 0; g < 4; ++g) {
          int brow = g*64 + jg*16 + cl;
          bf[g] = *(const f16x8*)(Bs + brow*64 + ((kc ^ (brow & 7))*8));
        }
#pragma unroll
        for (int mi = 0; mi < 4; ++mi)
#pragma unroll
          for (int g = 0; g < 4; ++g)
            acc[mi][g] = mfma16(af[mi], bf[g], acc[mi][g]);
      }
      __syncthreads();
    }

    // padded LDS restage epilogue (vectorized G/CS/HS access)
    f16* stg = smem;
#pragma unroll
    for (int half = 0; half < 2; ++half) {
      if (rg == half) {
#pragma unroll
        for (int mi = 0; mi < 4; ++mi)
#pragma unroll
          for (int g = 0; g < 4; ++g)
#pragma unroll
            for (int r = 0; r < 4; ++r) {
              int row_l = mi*16 + kq*4 + r;
              stg[row_l*264 + g*64 + jg*16 + cl] = (f16)acc[mi][g][r];
            }
      }
      __syncthreads();
      {
        int row_l = tid >> 3, sl = tid & 7;
        int slot = half*64 + row_l;
        int row = ridx[slot];
        if (row >= 0) {
          int jj = j0 + sl*8;
          f16x8 ai = *(const f16x8*)(stg + row_l*264 +        sl*8);
          f16x8 af2 = *(const f16x8*)(stg + row_l*264 +  64 + sl*8);
          f16x8 ag = *(const f16x8*)(stg + row_l*264 + 128 + sl*8);
          f16x8 ao = *(const f16x8*)(stg + row_l*264 + 192 + sl*8);
          f16x8 Gi = *(const f16x8*)(G + (size_t)row*NG +        jj);
          f16x8 Gf = *(const f16x8*)(G + (size_t)row*NG +  512 + jj);
          f16x8 Gg = *(const f16x8*)(G + (size_t)row*NG + 1024 + jj);
          f16x8 Go = *(const f16x8*)(G + (size_t)row*NG + 1536 + jj);
          f16x8 cp = *(const f16x8*)(CS + (size_t)(row - 1)*HH + jj);
          float m = rmk[slot];
          f16x8 hv, cv;
#pragma unroll
          for (int e = 0; e < 8; ++e) {
            float gi = (float)ai[e] + (float)Gi[e];
            float gf = (float)af2[e] + (float)Gf[e];
            float gg = (float)ag[e] + (float)Gg[e];
            float go = (float)ao[e] + (float)Go[e];
            float c = sigf(gf)*(float)cp[e] + sigf(gi)*tanh_(gg);
            float h = sigf(go)*tanh_(c);
            hv[e] = (f16)(h*m); cv[e] = (f16)(c*m);
          }
          *(f16x8*)(HS + (size_t)row*HH + jj) = hv;
          *(f16x8*)(CS + (size_t)row*HH + jj) = cv;
        }
      }
      __syncthreads();
    }
  }
}

// ---------------- bucket s (5..15): THIN tiled MFMA step, BK=128 (4 K-iters) ----------------
// unit = (128-row chunk) x (16-j chunk); 8 waves each own 16 rows; As[128][128], Bs[64][128]
__global__ __launch_bounds__(512) void lstm_step_thin(const f16* __restrict__ Wh,
    const f16* __restrict__ G, f16* __restrict__ HS, f16* __restrict__ CS,
    const float* __restrict__ mask, const int* __restrict__ counts,
    const int* __restrict__ lists, int s) {
  const int cnt = counts[s*32];
  if (cnt == 0) return;
  const int units = ((cnt + 127) >> 7) * 32;
  const int* lst = lists + d_OFF[s];
  const int tid = threadIdx.x;
  const int lane = tid & 63;
  const int w = tid >> 6;
  __shared__ __align__(16) f16 As[128*128];   // 32KB
  __shared__ __align__(16) f16 Bs[64*128];    // 16KB: brow = gate*16 + j
  __shared__ int ridx[128];
  __shared__ float rmk[128];
  const int cl = lane & 15;
  const int kq = lane >> 4;
  const int rbase = w * 16;

  for (int u = blockIdx.x; u < units; u += gridDim.x) {
    const int mbase = (u >> 5) * 128;
    const int j0 = (u & 31) * 16;
    if (tid < 128) {
      int i = mbase + tid;
      int r = (i < cnt) ? lst[i] : -1;
      ridx[tid] = r;
      rmk[tid] = (r >= 0) ? mask[r] : 0.0f;
    }
    __syncthreads();

    // staging addresses: A 4 chunks/thread, B 2 chunks/thread per K-iter (16B chunks, 16/row)
    const f16* asrc[4];
#pragma unroll
    for (int p = 0; p < 4; ++p) {
      int cid = tid + p*512;
      int r = cid >> 4, c = cid & 15;
      int cs = c ^ (r & 15);
      int rr = ridx[r];
      int sr = (rr >= 1 ? rr : 1) - 1;
      asrc[p] = HS + (size_t)sr*HH + cs*8;
    }
    const f16* bsrc[2];
#pragma unroll
    for (int p = 0; p < 2; ++p) {
      int cid = tid + p*512;
      int grow = cid >> 4, c = cid & 15;
      int cs = c ^ (grow & 15);
      int wrow = (grow >> 4)*512 + j0 + (grow & 15);
      bsrc[p] = Wh + (size_t)wrow*HH + cs*8;
    }

    f32x4 acc[4] = {};
    for (int k0 = 0; k0 < HH; k0 += 128) {
#pragma unroll
      for (int p = 0; p < 4; ++p)
        gload16(asrc[p] + k0, As + (tid + p*512)*8);
#pragma unroll
      for (int p = 0; p < 2; ++p)
        gload16(bsrc[p] + k0, Bs + (tid + p*512)*8);
      __syncthreads();
#pragma unroll
      for (int ks = 0; ks < 4; ++ks) {
        int kc = ks*4 + kq;
        int arow = rbase + cl;
        f16x8 af = *(const f16x8*)(As + arow*128 + ((kc ^ (arow & 15))*8));
        f16x8 bf[4];
#pragma unroll
        for (int g = 0; g < 4; ++g) {
          int brow = g*16 + cl;
          bf[g] = *(const f16x8*)(Bs + brow*128 + ((kc ^ (brow & 15))*8));
        }
#pragma unroll
        for (int g = 0; g < 4; ++g)
          acc[g] = mfma16(af, bf[g], acc[g]);
      }
      __syncthreads();
    }

    const int j = j0 + cl;
#pragma unroll
    for (int r = 0; r < 4; ++r) {
      int slot = rbase + kq*4 + r;
      int row = ridx[slot];
      if (row >= 0) {
        size_t gb = (size_t)row * NG;
        float gi = acc[0][r] + (float)G[gb + j];
        float gf = acc[1][r] + (float)G[gb + 512 + j];
        float gg = acc[2][r] + (float)G[gb + 1024 + j];
        float go = acc[3][r] + (float)G[gb + 1536 + j];
        float cp = (float)CS[(size_t)(row - 1)*HH + j];
        float c = sigf(gf)*cp + sigf(gi)*tanh_(gg);
        float h = sigf(go)*tanh_(c);
        float m = rmk[slot];
        HS[(size_t)row*HH + j] = (f16)(h*m);
        CS[(size_t)row*HH + j] = (f16)(c*m);
      }
    }
    __syncthreads();
  }
}

// ---------------- tail: run >= 16, sequential per batch (rare; coalesced matvec) ----------------
__global__ __launch_bounds__(512) void lstm_tail(const f16* __restrict__ Wh,
    const f16* __restrict__ G, f16* __restrict__ HS, f16* __restrict__ CS,
    const float* __restrict__ mask, const int* __restrict__ tailcnt,
    const int* __restrict__ taillist) {
  int b = blockIdx.x;
  int n = tailcnt[b];
  if (n == 0) return;
  int tid = threadIdx.x, lane = tid & 63, w = tid >> 6;
  const int rl = lane >> 3;
  const int kb = (lane & 7) * 8;
  __shared__ __align__(16) f16 hsh[HH];
  __shared__ float gsh[NG];
  for (int i = 0; i < n; ++i) {
    int t = taillist[b*TT + i];
    size_t row = (size_t)b*TT + t;
    if (tid < 256)
      ((uint32_t*)hsh)[tid] = ((const uint32_t*)(HS + (row - 1)*HH))[tid];
    __syncthreads();
    f16x8 hreg[8];
#pragma unroll
    for (int kk = 0; kk < 8; ++kk)
      hreg[kk] = *(const f16x8*)(hsh + kb + kk*64);
#pragma unroll 2
    for (int batch = 0; batch < 32; ++batch) {
      int o = (w*32 + batch)*8 + rl;
      const f16* wrow = Wh + (size_t)o*HH + kb;
      float p = 0.0f;
#pragma unroll
      for (int kk = 0; kk < 8; ++kk) {
        f16x8 wv = *(const f16x8*)(wrow + kk*64);
        f16x2 w0 = {wv[0], wv[1]}, w1 = {wv[2], wv[3]}, w2 = {wv[4], wv[5]}, w3 = {wv[6], wv[7]};
        f16x2 h0 = {hreg[kk][0], hreg[kk][1]}, h1 = {hreg[kk][2], hreg[kk][3]},
              h2 = {hreg[kk][4], hreg[kk][5]}, h3 = {hreg[kk][6], hreg[kk][7]};
        p = __builtin_amdgcn_fdot2(w0, h0, p, false);
        p = __builtin_amdgcn_fdot2(w1, h1, p, false);
        p = __builtin_amdgcn_fdot2(w2, h2, p, false);
        p = __builtin_amdgcn_fdot2(w3, h3, p, false);
      }
      p += __shfl_xor(p, 1);
      p += __shfl_xor(p, 2);
      p += __shfl_xor(p, 4);
      if ((lane & 7) == 0) gsh[o] = p + (float)G[row*NG + o];
    }
    __syncthreads();
    {
      float cp = (float)CS[(row - 1)*HH + tid];
      float c = sigf(gsh[512 + tid])*cp + sigf(gsh[tid])*tanh_(gsh[1024 + tid]);
      float h = sigf(gsh[1536 + tid])*tanh_(c);
      float m = mask[row];
      HS[row*HH + tid] = (f16)(h*m);
      CS[row*HH + tid] = (f16)(c*m);
    }
    __syncthreads();
  }
}

// ---------------- relu + layernorm, wave-per-row ----------------
__global__ __launch_bounds__(512) void ln_relu(const f16* __restrict__ in,
    const float* __restrict__ g, const float* __restrict__ be,
    f16* __restrict__ out) {
  int lane = threadIdx.x & 63, w = threadIdx.x >> 6;
  int row = blockIdx.x * 8 + w;
  f16x8 hv = *(const f16x8*)(in + (size_t)row*HH + lane*8);
  float xv[8]; float s1 = 0.f, s2 = 0.f;
#pragma unroll
  for (int e = 0; e < 8; ++e) { float x = fmaxf((float)hv[e], 0.f); xv[e] = x; s1 += x; s2 += x*x; }
#pragma unroll
  for (int o = 1; o < 64; o <<= 1) { s1 += __shfl_xor(s1, o); s2 += __shfl_xor(s2, o); }
  float mu = s1 * (1.0f/512.0f);
  float var = s2 * (1.0f/512.0f) - mu*mu;
  float rs = rsqrtf(var + 1e-5f);
  f16x8 ov;
#pragma unroll
  for (int e = 0; e < 8; ++e) ov[e] = (f16)((xv[e] - mu)*rs*g[lane*8+e] + be[lane*8+e]);
  *(f16x8*)(out + (size_t)row*HH + lane*8) = ov;
}

// ---------------- fused head: relu+LN of last hidden state, then FC to 1000 classes ----------------
__global__ __launch_bounds__(512) void head_fused(const f16* __restrict__ HS,
    const float* __restrict__ g, const float* __restrict__ be,
    const float* __restrict__ W, const float* __restrict__ bias, float* __restrict__ out) {
  int b = blockIdx.x;
  int j = threadIdx.x;
  __shared__ float hsh[512];
  float x = fmaxf((float)HS[((size_t)b*TT + (TT-1))*HH + j], 0.0f);
  float s1 = x, s2 = x*x;
  for (int o = 32; o > 0; o >>= 1) { s1 += __shfl_down(s1, o); s2 += __shfl_down(s2, o); }
  __shared__ float a1[8], a2[8];
  int w = j >> 6;
  if ((j & 63) == 0) { a1[w] = s1; a2[w] = s2; }
  __syncthreads();
  if (j == 0) {
    float t1 = 0.f, t2 = 0.f;
    for (int i = 0; i < 8; ++i) { t1 += a1[i]; t2 += a2[i]; }
    a1[0] = t1; a2[0] = t2;
  }
  __syncthreads();
  float mu = a1[0] * (1.0f/512.0f);
  float var = a2[0] * (1.0f/512.0f) - mu*mu;
  hsh[j] = (x - mu) * rsqrtf(var + 1e-5f) * g[j] + be[j];
  __syncthreads();
#pragma unroll
  for (int rep = 0; rep < 2; ++rep) {
    int c = j + rep*512;
    if (c < NCLS) {
      const float4* wr = (const float4*)(W + (size_t)c*HH);
      float acc = bias[c];
#pragma unroll 4
      for (int k4 = 0; k4 < 128; ++k4) {
        float4 wv = wr[k4];
        acc += wv.x*hsh[k4*4] + wv.y*hsh[k4*4+1] + wv.z*hsh[k4*4+2] + wv.w*hsh[k4*4+3];
      }
      out[b*NCLS + c] = acc;
    }
  }
}

extern "C" void kernel_launch(void* const* d_in, const int* in_sizes, int n_in,
                              void* d_out, int out_size, void* d_ws, size_t ws_size,
                              hipStream_t stream) {
  (void)in_sizes; (void)n_in; (void)out_size;
  const float* x    = (const float*)d_in[0];
  const float* mask = (const float*)d_in[1];
  const float* Wih0 = (const float*)d_in[2];
  const float* Whh0 = (const float*)d_in[3];
  const float* bih0 = (const float*)d_in[4];
  const float* bhh0 = (const float*)d_in[5];
  const float* g0   = (const float*)d_in[6];
  const float* be0  = (const float*)d_in[7];
  const float* Wih1 = (const float*)d_in[8];
  const float* Whh1 = (const float*)d_in[9];
  const float* bih1 = (const float*)d_in[10];
  const float* bhh1 = (const float*)d_in[11];
  const float* g1   = (const float*)d_in[12];
  const float* be1  = (const float*)d_in[13];
  const float* fcW  = (const float*)d_in[14];
  const float* fcb  = (const float*)d_in[15];
  float* out = (float*)d_out;

  char* ws = (char*)d_ws;
  size_t off = 0;
  auto alloc = [&](size_t bytes) { size_t o = off; off += (bytes + 255) & ~(size_t)255; return o; };
  f16* G      = (f16*)(ws + alloc((size_t)BT*NG*2));
  f16* HS     = (f16*)(ws + alloc((size_t)BT*HH*2));
  f16* CS     = (f16*)(ws + alloc((size_t)BT*HH*2));
  f16* H0LN   = (f16*)(ws + alloc((size_t)BT*HH*2));
  f16* W16ih0 = (f16*)(ws + alloc((size_t)NG*DD*2));
  f16* W16hh0 = (f16*)(ws + alloc((size_t)NG*HH*2));
  f16* W16ih1 = (f16*)(ws + alloc((size_t)NG*HH*2));
  f16* W16hh1 = (f16*)(ws + alloc((size_t)NG*HH*2));
  float* bias0 = (float*)(ws + alloc(NG*4));
  float* bias1 = (float*)(ws + alloc(NG*4));
  int* counts  = (int*)(ws + alloc(4096));       // counts[s*32], s=0..15 | tailcnt @ +512
  int* tailcnt = counts + 512;
  int* lists   = (int*)(ws + alloc(111168*4));
  int* taillist= (int*)(ws + alloc((size_t)BT*4));
  float* selm  = (float*)(ws + alloc((size_t)BT*4));
  if (ws_size < off) return;

  f16* AX = H0LN;  // x-f16 region, consumed by proj_act L0 before H0LN written

  hipMemsetAsync(counts, 0, 4096, stream);
  prep_weights<<<dim3(512), dim3(256), 0, stream>>>(Wih0, Whh0, Wih1, Whh1, x,
      bih0, bhh0, bih1, bhh1, W16ih0, W16hh0, W16ih1, W16hh1, AX, bias0, bias1);
  build_lists<<<dim3(BB), dim3(512), 0, stream>>>(mask, counts, lists, tailcnt, taillist, selm);

  for (int layer = 0; layer < 2; ++layer) {
    const f16* Wih16 = layer ? W16ih1 : W16ih0;
    const f16* Whh16 = layer ? W16hh1 : W16hh0;
    const float* bias = layer ? bias1 : bias0;
    const f16* Ain = layer ? H0LN : AX;
    int K = layer ? HH : DD;
    proj_act<<<dim3((BT/128)*8), dim3(512), 0, stream>>>(Ain, Wih16, bias, G, HS, CS, selm, K);
    for (int s = 1; s < 5; ++s)
      lstm_step<<<dim3(512), dim3(512), 0, stream>>>(Whh16, G, HS, CS, mask, counts, lists, s);
    for (int s = 5; s < MAXS; ++s)
      lstm_step_thin<<<dim3(128), dim3(512), 0, stream>>>(Whh16, G, HS, CS, mask, counts, lists, s);
    lstm_tail<<<dim3(BB), dim3(512), 0, stream>>>(Whh16, G, HS, CS, mask, tailcnt, taillist);
    if (layer == 0)
      ln_relu<<<dim3(BT/8), dim3(512), 0, stream>>>(HS, g0, be0, H0LN);
  }

  head_fused<<<dim3(BB), dim3(512), 0, stream>>>(HS, g1, be1, fcW, fcb, out);
}